// Round 12
// baseline (38.693 us; speedup 1.0000x reference)
//
#include <hip/hip_runtime.h>

// Maj3: out[b,o,h,w] = sum_{kh,c} sign( sum_{kw} x[b,c,h+kh-1,w+kw-1] * W[o,kw,kh,c] )
// x: (4,64,56,56) f32; W: (64,3,3,64) f32; out: (4,64,56,56) f32.
// Bit-exactness vs numpy required (integer output, threshold 1.36): no FMA
// contraction (contract(off) pragma — verified holding, absmax stable 1.0),
// same per-channel mul/add order, sign(0)=0 only from fully-pad rows (skipped).
//
// R12: R11 stalls (~50%) are the SMEM weight stream — out-of-order s_load
// returns force lgkmcnt(0) drains per tile, and the ~96-SGPR budget caps the
// tile (R10: exceeding it = scalar spill disaster). Fix: stage the block's
// 18.4 KB weight slice into LDS once (bit-exact), consume via broadcast
// ds_read_b128 (3 float4 per oo-subtile, just-in-time, 12 VGPRs live). DS is
// in-order -> compiler emits partial lgkmcnt waits and pipelines reads under
// the previous oo's ~56 VALU ops. No SMEM in the main loop at all. x-loads
// keep R11's one-tile-ahead prefetch. Combine buffer aliases the weight LDS.

#define Cn 64
#define Hn 56
#define Wn 56
#define On 64
#define OG 8    // output channels per block
#define CH 16   // channels per wave (c-quarter); power of 2 (wrap mask)

#define DPP_WAVE_SHL1 0x130
#define DPP_WAVE_SHR1 0x138

// Whole-wave shift by one lane; out-of-range source lanes read 0 (exact pad).
__device__ __forceinline__ float dpp_shift(float s, const int ctrl_is_shr) {
    const int si = __builtin_bit_cast(int, s);
    const int r  = ctrl_is_shr
        ? __builtin_amdgcn_update_dpp(0, si, DPP_WAVE_SHR1, 0xf, 0xf, true)
        : __builtin_amdgcn_update_dpp(0, si, DPP_WAVE_SHL1, 0xf, 0xf, true);
    return __builtin_bit_cast(float, r);
}

__global__ __launch_bounds__(256, 6)
void maj3_kernel(const float* __restrict__ x,
                 const float* __restrict__ wt,
                 float* __restrict__ out)
{
#pragma clang fp contract(off)
    // 18432 B: weight slice [oo][kw][kh][c] (same layout as wt); the combine
    // buffer aliases the front of it after compute (sync-guarded).
    __shared__ __align__(16) char smem[OG * 9 * Cn * 4];
    float* wlds = (float*)smem;

    const int lane = threadIdx.x & 63;
    // Wave-uniform; readfirstlane keeps derived values on the scalar path.
    const int cq   = __builtin_amdgcn_readfirstlane((int)(threadIdx.x >> 6)); // 0..3
    const int bh   = blockIdx.x;        // 0..223: one (b,h) row per block
    const int b    = bh / Hn;
    const int h    = bh - b * Hn;
    const int og   = blockIdx.y * OG;   // block-uniform o base

    // Stage this block's weight slice into LDS (bit-exact copy, coalesced).
    {
        const float4* src = (const float4*)(wt + og * (9 * Cn));
        float4* dst = (float4*)wlds;
        for (int i = threadIdx.x; i < (OG * 9 * Cn) / 4; i += 256)
            dst[i] = src[i];
    }
    __syncthreads();

    const int wc   = lane;              // pixel column; lanes >=56 inactive
    const bool act = wc < Wn;
    const int c1   = min(wc, Wn - 1);   // clamped own-tap address

#define LDX(cc) (act ? xr[(cc) * (Hn * Wn) + c1] : 0.0f)

    int acc[OG];
    #pragma unroll
    for (int i = 0; i < OG; ++i) acc[i] = 0;

    int nvalid = 0;
    const float* xb = x + b * (Cn * Hn * Wn) + cq * (CH * Hn * Wn);

    for (int kh = 0; kh < 3; ++kh) {
        const int row = h + kh - 1;
        if (row < 0 || row >= Hn) continue;   // fully-pad row: sign(0)=0, skip
        ++nvalid;
        const float* xr = xb + row * Wn;

        // Prologue: tile 0's x values in named regs (one-tile-ahead pipeline).
        float xa0 = LDX(0), xa1 = LDX(1), xa2 = LDX(2), xa3 = LDX(3);

        #pragma clang loop unroll(disable)
        for (int ct = 0; ct < CH; ct += 4) {
            // Prefetch next x tile (wraps on last iter: harmless reload).
            const int cn = (ct + 4) & (CH - 1);
            const float nb0 = LDX(cn + 0);
            const float nb1 = LDX(cn + 1);
            const float nb2 = LDX(cn + 2);
            const float nb3 = LDX(cn + 3);

            // Neighbor taps once per channel, shared across all 8 oo.
            const float xl0 = dpp_shift(xa0, 1), xh0 = dpp_shift(xa0, 0);
            const float xl1 = dpp_shift(xa1, 1), xh1 = dpp_shift(xa1, 0);
            const float xl2 = dpp_shift(xa2, 1), xh2 = dpp_shift(xa2, 0);
            const float xl3 = dpp_shift(xa3, 1), xh3 = dpp_shift(xa3, 0);

            #pragma unroll
            for (int oo = 0; oo < OG; ++oo) {
                // wlds[(oo*9 + kw*3 + kh)*64 + cq*16 + ct .. +3], kw = 0,1,2:
                const int wbase = (oo * 9 + kh) * Cn + cq * CH + ct;
                const float4 w0 = *(const float4*)&wlds[wbase + 0 * 3 * Cn];
                const float4 w1 = *(const float4*)&wlds[wbase + 1 * 3 * Cn];
                const float4 w2 = *(const float4*)&wlds[wbase + 2 * 3 * Cn];
                // Per channel: p0=x[w-1]*W(kw0), p1=x[w]*W(kw1), p2=x[w+1]*W(kw2),
                // s=(p0+p1)+p2 — reference order, contract(off).
                const float s0 = (xl0 * w0.x + xa0 * w1.x) + xh0 * w2.x;
                const float s1 = (xl1 * w0.y + xa1 * w1.y) + xh1 * w2.y;
                const float s2 = (xl2 * w0.z + xa2 * w1.z) + xh2 * w2.z;
                const float s3 = (xl3 * w0.w + xa3 * w1.w) + xh3 * w2.w;
                // Integer negative-count (exact): paired adds -> v_add3.
                acc[oo] += (int)(((__float_as_uint(s0) >> 31) +
                                  (__float_as_uint(s1) >> 31)) +
                                 ((__float_as_uint(s2) >> 31) +
                                  (__float_as_uint(s3) >> 31)));
            }
            xa0 = nb0; xa1 = nb1; xa2 = nb2; xa3 = nb3;
        }
    }

    // Reuse the weight LDS as the combine buffer (all reads are done).
    __syncthreads();
    int (*cbuf)[OG][64] = (int (*)[OG][64])smem;
    if (cq != 0) {
        #pragma unroll
        for (int oo = 0; oo < OG; ++oo) cbuf[cq - 1][oo][lane] = acc[oo];
    }
    __syncthreads();
    if (cq == 0 && act) {
        float* ob = out + ((b * On + og) * Hn + h) * Wn + wc;
        const float base = (float)(nvalid * Cn);
        #pragma unroll
        for (int oo = 0; oo < OG; ++oo) {
            const int total = acc[oo] + cbuf[0][oo][lane]
                            + cbuf[1][oo][lane] + cbuf[2][oo][lane];
            ob[oo * Hn * Wn] = base - 2.0f * (float)total;  // N - 2*negcount
        }
    }
}

extern "C" void kernel_launch(void* const* d_in, const int* in_sizes, int n_in,
                              void* d_out, int out_size, void* d_ws, size_t ws_size,
                              hipStream_t stream) {
    const float* x  = (const float*)d_in[0];
    const float* wt = (const float*)d_in[1];
    float* o        = (float*)d_out;
    dim3 grid(224, 8);   // 224 (b,h) rows x 8 o-groups of 8
    maj3_kernel<<<grid, dim3(256), 0, stream>>>(x, wt, o);
}